// Round 8
// baseline (326.764 us; speedup 1.0000x reference)
//
#include <hip/hip_runtime.h>

#define B_    8
#define N_    8192
#define S_    2048
#define D1_   128
#define D2_   256
#define CIN_  384
#define CMID_ 256
#define COUT_ 256

typedef unsigned int  u32;
typedef unsigned short u16;
typedef __attribute__((ext_vector_type(8))) short short8;
typedef __attribute__((ext_vector_type(4))) float f32x4;

static __device__ __forceinline__ u32 uminu(u32 a, u32 b) { return a < b ? a : b; }
static __device__ __forceinline__ u32 umed3(u32 a, u32 b, u32 c) {
  u32 d;
  asm("v_med3_u32 %0, %1, %2, %3" : "=v"(d) : "v"(a), "v"(b), "v"(c));
  return d;
}
static __device__ __forceinline__ u16 f2bf(float f) {
  union { float f; u32 u; } v; v.f = f;
  u32 r = v.u + 0x7FFFu + ((v.u >> 16) & 1u);  // RNE
  return (u16)(r >> 16);
}
static __device__ __forceinline__ float bflo(u32 u) { return __uint_as_float(u << 16); }
static __device__ __forceinline__ float bfhi(u32 u) { return __uint_as_float(u & 0xFFFF0000u); }
static __device__ __forceinline__ u32 cvtpk_bf16(float lo, float hi) {
  u32 d;
  asm("v_cvt_pk_bf16_f32 %0, %1, %2" : "=v"(d) : "v"(lo), "v"(hi));
  return d;
}

#define GLD16(g, l)                                                             \
  __builtin_amdgcn_global_load_lds((const __attribute__((address_space(1))) void*)(g), \
                                   (__attribute__((address_space(3))) void*)(l), 16, 0, 0)

// Counted-vmcnt pipeline barrier (T3/T4), race-safe order (round-6 proven):
// wait+barrier FIRST, then stage into the freed buffer.
#define WB(N)                                                                   \
  __builtin_amdgcn_sched_barrier(0);                                            \
  asm volatile("s_waitcnt vmcnt(" #N ")" ::: "memory");                         \
  __builtin_amdgcn_s_barrier();                                                 \
  __builtin_amdgcn_sched_barrier(0);

// ---------------------------------------------------------------------------
// Fused preprocessing, one launch, block-range decode:
//   blocks [0, 4096)        : p2t  transpose points2 -> p2T
//   blocks [4096, 12288)    : packp1 points1 -> xT[.., 0..127] bf16
//   blocks [12288, 12992)   : pre  pts4 + w1/w2 bf16 convert
// ---------------------------------------------------------------------------
__global__ __launch_bounds__(256) void k_pre_all(const float* __restrict__ xyz2,
                                                 float4* __restrict__ pts4,
                                                 const float* __restrict__ w1,
                                                 const float* __restrict__ w2,
                                                 u16* __restrict__ w1b,
                                                 u16* __restrict__ w2b,
                                                 const float* __restrict__ p2,
                                                 float* __restrict__ p2T,
                                                 const float* __restrict__ p1,
                                                 u16* __restrict__ xT) {
  __shared__ float t[32][33];
  const int blk = blockIdx.x;
  const int cc = threadIdx.x & 31, rr = threadIdx.x >> 5;
  if (blk < 4096) {
    // p2t: [b][256][2048] -> [b][2048][256]
    const int s0 = (blk & 63) * 32, d0 = ((blk >> 6) & 7) * 32, b = blk >> 9;
#pragma unroll
    for (int i = 0; i < 4; ++i) {
      int r = rr + i * 8;
      t[r][cc] = p2[((size_t)b * D2_ + d0 + r) * S_ + s0 + cc];
    }
    __syncthreads();
#pragma unroll
    for (int i = 0; i < 4; ++i) {
      int r = rr + i * 8;
      p2T[((size_t)b * S_ + s0 + r) * D2_ + d0 + cc] = t[cc][r];
    }
    return;
  }
  if (blk < 12288) {
    // packp1: [b][128][N] -> xT[b][n][0..127] bf16
    const int idx = blk - 4096;
    const int n0 = (idx & 255) * 32, c0 = ((idx >> 8) & 3) * 32, b = idx >> 10;
#pragma unroll
    for (int i = 0; i < 4; ++i) {
      int r = rr + i * 8;
      t[r][cc] = p1[((size_t)b * D1_ + c0 + r) * N_ + n0 + cc];
    }
    __syncthreads();
#pragma unroll
    for (int i = 0; i < 4; ++i) {
      int r = rr + i * 8;
      xT[((size_t)b * N_ + n0 + r) * CIN_ + c0 + cc] = f2bf(t[cc][r]);
    }
    return;
  }
  const int i = (blk - 12288) * 256 + threadIdx.x;
  if (i < B_ * S_) {
    const int b = i >> 11, s = i & (S_ - 1);
    const float* xb = xyz2 + (size_t)b * 3 * S_;
    float x = xb[s], y = xb[S_ + s], z = xb[2 * S_ + s];
    pts4[b * S_ + s] = make_float4(-2.f * x, -2.f * y, -2.f * z, x * x + y * y + z * z);
    return;
  }
  const int j = i - B_ * S_;
  if (j < CMID_ * CIN_) { w1b[j] = f2bf(w1[j]); return; }
  const int h = j - CMID_ * CIN_;
  if (h < COUT_ * CMID_) w2b[h] = f2bf(w2[h]);
}

// ---------------------------------------------------------------------------
// FUSED NN screen + refine. Per thread: scan 4 chunks of 512 candidates
// sequentially; per chunk keep quantized top-3 keys (3-op maintenance,
// key = (bits & 0xFFFFFE00) | s_local); after each chunk, fp64-refine its
// 3 candidates into the running exact top-3. Identical composition to the
// previous nn_scan + refine pair (same insertion order, same keys) with
// zero keys traffic.
// ---------------------------------------------------------------------------
__global__ __launch_bounds__(256) void k_nnref(const float* __restrict__ xyz1,
                                               const float4* __restrict__ pts4,
                                               int4* __restrict__ idx4,
                                               float4* __restrict__ w4) {
  const int b = blockIdx.y, n = blockIdx.x * 256 + threadIdx.x;
  const float* pb = xyz1 + (size_t)b * 3 * N_;
  const float px = pb[n], py = pb[N_ + n], pz = pb[2 * N_ + n];
  const float pn = px * px + py * py + pz * pz;
  const double dpx = (double)px, dpy = (double)py, dpz = (double)pz;
  const double dpn = dpx * dpx + dpy * dpy + dpz * dpz;
  double bd0 = 1e300, bd1 = 1e300, bd2 = 1e300;
  int bi0 = 1 << 30, bi1 = 1 << 30, bi2 = 1 << 30;
#pragma unroll
  for (int chunk = 0; chunk < 4; ++chunk) {
    const float4* __restrict__ P = pts4 + b * S_ + chunk * 512;
    u32 m0 = ~0u, m1 = ~0u, m2 = ~0u;
#pragma unroll 8
    for (int s = 0; s < 512; ++s) {
      float4 q = P[s];  // uniform address -> s_load_dwordx4
      float d = fmaf(px, q.x, fmaf(py, q.y, fmaf(pz, q.z, pn + q.w)));
      d = fmaxf(d, 0.f);
      u32 k = (__float_as_uint(d) & 0xFFFFFE00u) | (u32)s;
      u32 m2n = umed3(m1, m2, k);     // old m1, m2: new 3rd-smallest
      m1 = umed3(m0, m1, k);          // old m0, m1
      m0 = uminu(m0, k);
      m2 = m2n;
    }
    // exact fp64 refine of this chunk's 3 candidates (same order as before)
    u32 arr[3] = {m0, m1, m2};
#pragma unroll
    for (int j = 0; j < 3; ++j) {
      int s = chunk * 512 + (int)(arr[j] & 511u);
      float4 q = pts4[b * S_ + s];
      double x = (double)(q.x * -0.5f), y = (double)(q.y * -0.5f), z = (double)(q.z * -0.5f);
      double dot = dpx * x + dpy * y + dpz * z;
      double d = -2.0 * dot + (dpn + (x * x + y * y + z * z));
      if (d < bd2 || (d == bd2 && s < bi2)) {
        if (d < bd1 || (d == bd1 && s < bi1)) {
          bd2 = bd1; bi2 = bi1;
          if (d < bd0 || (d == bd0 && s < bi0)) { bd1 = bd0; bi1 = bi0; bd0 = d; bi0 = s; }
          else                                  { bd1 = d;  bi1 = s; }
        } else { bd2 = d; bi2 = s; }
      }
    }
  }
  float f0 = (float)bd0, f1 = (float)bd1, f2 = (float)bd2;
  float r0 = 1.f / (f0 + 1e-8f), r1 = 1.f / (f1 + 1e-8f), r2 = 1.f / (f2 + 1e-8f);
  float rs = r0 + r1 + r2;
  w4[(size_t)b * N_ + n]   = make_float4(r0 / rs, r1 / rs, r2 / rs, 0.f);
  idx4[(size_t)b * N_ + n] = make_int4(bi0, bi1, bi2, 0);
}

// ---------------------------------------------------------------------------
// Gather+interp into xT[b][n][128..383] bf16. One WAVE per point n.
// ---------------------------------------------------------------------------
__global__ __launch_bounds__(256) void k_gather_pack(const float* __restrict__ p2T,
                                                     const int4* __restrict__ idx4,
                                                     const float4* __restrict__ w4,
                                                     u16* __restrict__ xT) {
  const int b = blockIdx.y;
  const int wv = threadIdx.x >> 6, lane = threadIdx.x & 63;
  const int nbase = blockIdx.x * 16 + wv * 4;
  int4   id[4];
  float4 w[4];
#pragma unroll
  for (int i = 0; i < 4; ++i) {
    id[i] = idx4[(size_t)b * N_ + nbase + i];
    w[i]  = w4[(size_t)b * N_ + nbase + i];
  }
#pragma unroll
  for (int i = 0; i < 4; ++i) {
    const int n = nbase + i;
    const float4* r0 = (const float4*)(p2T + ((size_t)b * S_ + id[i].x) * D2_) + lane;
    const float4* r1 = (const float4*)(p2T + ((size_t)b * S_ + id[i].y) * D2_) + lane;
    const float4* r2 = (const float4*)(p2T + ((size_t)b * S_ + id[i].z) * D2_) + lane;
    float4 a = *r0, bb = *r1, cq = *r2;
    ushort4 pk;
    pk.x = f2bf(a.x * w[i].x + bb.x * w[i].y + cq.x * w[i].z);
    pk.y = f2bf(a.y * w[i].x + bb.y * w[i].y + cq.y * w[i].z);
    pk.z = f2bf(a.z * w[i].x + bb.z * w[i].y + cq.z * w[i].z);
    pk.w = f2bf(a.w * w[i].x + bb.w * w[i].y + cq.w * w[i].z);
    *(ushort4*)(xT + ((size_t)b * N_ + n) * CIN_ + D1_ + lane * 4) = pk;
  }
}

// ---------------------------------------------------------------------------
// BN stats reduction + affine: one wave per channel o. partials [512][256].
// ---------------------------------------------------------------------------
__global__ __launch_bounds__(64) void k_bnstat(const float* __restrict__ ps,
                                               const float* __restrict__ pq,
                                               const float* __restrict__ g,
                                               const float* __restrict__ beta,
                                               float* __restrict__ scale,
                                               float* __restrict__ shift) {
  const int o = blockIdx.x, l = threadIdx.x;
  float s = 0.f, q = 0.f;
#pragma unroll
  for (int i = 0; i < 8; ++i) {
    s += ps[(size_t)(i * 64 + l) * 256 + o];
    q += pq[(size_t)(i * 64 + l) * 256 + o];
  }
#pragma unroll
  for (int m = 1; m <= 32; m <<= 1) { s += __shfl_xor(s, m); q += __shfl_xor(q, m); }
  if (l == 0) {
    const float inv = 1.0f / (float)(B_ * N_);
    float mean = s * inv;
    float var = q * inv - mean * mean;
    float sc = g[o] / sqrtf(var + 1e-5f);
    scale[o] = sc;
    shift[o] = beta[o] - mean * sc;
  }
}

// ---------------------------------------------------------------------------
// GEMM1 (bf16 MFMA), FULL-M tile, triple-buffered LDS, counted-vmcnt
// pipeline (round-6 verified form, unchanged).
// ---------------------------------------------------------------------------
__global__ __launch_bounds__(512) void k_gemm1(const u16* __restrict__ Wb,
                                               const float* __restrict__ bias,
                                               const u16* __restrict__ xT,
                                               u16* __restrict__ y1T,
                                               float* __restrict__ psum,
                                               float* __restrict__ pssq) {
  __shared__ u16 As[3][8192];   // 256 rows x 32 k per buffer
  __shared__ u16 Bs[3][4096];   // 128 rows x 32 k per buffer
  __shared__ float s_sum[256], s_ssq[256];
  const int b = blockIdx.z, bn0 = blockIdx.x * 128;
  const int tid = threadIdx.x, w = tid >> 6, l = tid & 63;
  const int wm = w & 3, wn = w >> 2;
  const int lr = l >> 2, lc = l & 3;
  const int fm = l & 15, fq = l >> 4;
  const int clog = (lc ^ ((lr >> 1) & 3)) * 8;   // staging source k-chunk
  const int swz8 = (fq ^ ((fm >> 1) & 3)) * 8;   // fragment phys k-chunk
  f32x4 acc[4][4];
#pragma unroll
  for (int i = 0; i < 4; ++i)
#pragma unroll
    for (int j = 0; j < 4; ++j) acc[i][j] = (f32x4){0.f, 0.f, 0.f, 0.f};

  const int NK = CIN_ / 32;  // 12

#define STAGE1(kk, buf)                                                         \
  {                                                                             \
    const int k0_ = (kk) * 32;                                                  \
    _Pragma("unroll") for (int j_ = 0; j_ < 2; ++j_) {                          \
      int seg_ = w * 2 + j_, row_ = seg_ * 16 + lr;                             \
      GLD16(Wb + (size_t)row_ * CIN_ + k0_ + clog, &As[buf][seg_ * 512]);       \
    }                                                                           \
    int brow_ = w * 16 + lr;                                                    \
    GLD16(xT + ((size_t)b * N_ + bn0 + brow_) * CIN_ + k0_ + clog,              \
          &Bs[buf][w * 512]);                                                   \
  }

  STAGE1(0, 0);
  STAGE1(1, 1);
  int cur = 0;
  for (int kk = 0; kk < NK; ++kk) {
    if (kk + 1 < NK) { WB(3) } else { WB(0) }
    if (kk + 2 < NK) {
      int bt = cur + 2; if (bt >= 3) bt -= 3;
      STAGE1(kk + 2, bt);
    }
    short8 af[4], bfr[4];
#pragma unroll
    for (int f = 0; f < 4; ++f) {
      af[f]  = *(const short8*)&As[cur][(wm * 64 + f * 16 + fm) * 32 + swz8];
      bfr[f] = *(const short8*)&Bs[cur][(wn * 64 + f * 16 + fm) * 32 + swz8];
    }
#pragma unroll
    for (int i = 0; i < 4; ++i)
#pragma unroll
      for (int j = 0; j < 4; ++j)
        acc[i][j] = __builtin_amdgcn_mfma_f32_16x16x32_bf16(af[i], bfr[j], acc[i][j], 0, 0, 0);
    ++cur; if (cur == 3) cur = 0;
  }
#undef STAGE1

  if (tid < 256) { s_sum[tid] = 0.f; s_ssq[tid] = 0.f; }
  __syncthreads();
  u16* tb = y1T + ((size_t)b * 64 + (bn0 >> 7)) * 32768;
#pragma unroll
  for (int i = 0; i < 4; ++i) {
    int ob = wm * 64 + i * 16 + fq * 4;
    float4 b4 = *(const float4*)(bias + ob);
    float sv0 = 0, sv1 = 0, sv2 = 0, sv3 = 0, qv0 = 0, qv1 = 0, qv2 = 0, qv3 = 0;
#pragma unroll
    for (int j = 0; j < 4; ++j) {
      int nl = wn * 64 + j * 16 + fm;
      ushort4 pk;
      pk.x = f2bf(acc[i][j][0] + b4.x);
      pk.y = f2bf(acc[i][j][1] + b4.y);
      pk.z = f2bf(acc[i][j][2] + b4.z);
      pk.w = f2bf(acc[i][j][3] + b4.w);
      *(ushort4*)(tb + (size_t)(ob >> 5) * 4096 + nl * 32 + (ob & 31)) = pk;
      float v0 = bflo(pk.x), v1 = bflo(pk.y), v2 = bflo(pk.z), v3 = bflo(pk.w);
      sv0 += v0; sv1 += v1; sv2 += v2; sv3 += v3;
      qv0 = fmaf(v0, v0, qv0); qv1 = fmaf(v1, v1, qv1);
      qv2 = fmaf(v2, v2, qv2); qv3 = fmaf(v3, v3, qv3);
    }
#pragma unroll
    for (int m = 1; m <= 8; m <<= 1) {
      sv0 += __shfl_xor(sv0, m); sv1 += __shfl_xor(sv1, m);
      sv2 += __shfl_xor(sv2, m); sv3 += __shfl_xor(sv3, m);
      qv0 += __shfl_xor(qv0, m); qv1 += __shfl_xor(qv1, m);
      qv2 += __shfl_xor(qv2, m); qv3 += __shfl_xor(qv3, m);
    }
    if (fm == 0) {
      atomicAdd(&s_sum[ob + 0], sv0); atomicAdd(&s_sum[ob + 1], sv1);
      atomicAdd(&s_sum[ob + 2], sv2); atomicAdd(&s_sum[ob + 3], sv3);
      atomicAdd(&s_ssq[ob + 0], qv0); atomicAdd(&s_ssq[ob + 1], qv1);
      atomicAdd(&s_ssq[ob + 2], qv2); atomicAdd(&s_ssq[ob + 3], qv3);
    }
  }
  __syncthreads();
  if (tid < 256) {
    const int blk = blockIdx.x + 64 * blockIdx.z;   // 0..511
    psum[(size_t)blk * 256 + tid] = s_sum[tid];
    pssq[(size_t)blk * 256 + tid] = s_ssq[tid];
  }
}

// ---------------------------------------------------------------------------
// GEMM2 (bf16 MFMA), FULL-M tile, same pipeline (round-6 form, unchanged).
// ---------------------------------------------------------------------------
__global__ __launch_bounds__(512) void k_gemm2(const u16* __restrict__ Wb2,
                                               const float* __restrict__ b2,
                                               const u16* __restrict__ y1T,
                                               const float* __restrict__ scale,
                                               const float* __restrict__ shift,
                                               u16* __restrict__ y2T,
                                               float* __restrict__ psum,
                                               float* __restrict__ pssq) {
  __shared__ u16 As[3][8192];
  __shared__ u16 Bs[3][4096];
  __shared__ float s_sum[256], s_ssq[256];
  __shared__ float s_sc[CMID_], s_sh[CMID_];
  const int b = blockIdx.z, bn0 = blockIdx.x * 128;
  const int tid = threadIdx.x, w = tid >> 6, l = tid & 63;
  const int wm = w & 3, wn = w >> 2;
  const int lr = l >> 2, lc = l & 3;
  const int fm = l & 15, fq = l >> 4;
  const int clog = (lc ^ ((lr >> 1) & 3)) * 8;
  const int swz8 = (fq ^ ((fm >> 1) & 3)) * 8;
  if (tid < 256) {
    s_sc[tid] = scale[tid];
    s_sh[tid] = shift[tid];
  }
  f32x4 acc[4][4];
#pragma unroll
  for (int i = 0; i < 4; ++i)
#pragma unroll
    for (int j = 0; j < 4; ++j) acc[i][j] = (f32x4){0.f, 0.f, 0.f, 0.f};

  const u16* tb = y1T + ((size_t)b * 64 + (bn0 >> 7)) * 32768;
  const int NK = CMID_ / 32;  // 8

#define STAGE2(kk, buf)                                                         \
  {                                                                             \
    const int k0_ = (kk) * 32;                                                  \
    _Pragma("unroll") for (int j_ = 0; j_ < 2; ++j_) {                          \
      int seg_ = w * 2 + j_, row_ = seg_ * 16 + lr;                             \
      GLD16(Wb2 + (size_t)row_ * CMID_ + k0_ + clog, &As[buf][seg_ * 512]);     \
    }                                                                           \
    int brow_ = w * 16 + lr;                                                    \
    GLD16(tb + (size_t)(kk) * 4096 + brow_ * 32 + clog, &Bs[buf][w * 512]);     \
  }

  STAGE2(0, 0);
  STAGE2(1, 1);
  int cur = 0;
  for (int kk = 0; kk < NK; ++kk) {
    if (kk + 1 < NK) { WB(3) } else { WB(0) }   // also covers s_sc/s_sh init
    if (kk + 2 < NK) {
      int bt = cur + 2; if (bt >= 3) bt -= 3;
      STAGE2(kk + 2, bt);
    }
    const int kb = kk * 32 + fq * 8;
    float4 s0 = *(const float4*)&s_sc[kb], s1 = *(const float4*)&s_sc[kb + 4];
    float4 h0 = *(const float4*)&s_sh[kb], h1 = *(const float4*)&s_sh[kb + 4];
    short8 af[4], bfr[4];
#pragma unroll
    for (int f = 0; f < 4; ++f) {
      af[f] = *(const short8*)&As[cur][(wm * 64 + f * 16 + fm) * 32 + swz8];
      uint4 r = *(const uint4*)&Bs[cur][(wn * 64 + f * 16 + fm) * 32 + swz8];
      float v0 = fmaxf(fmaf(bflo(r.x), s0.x, h0.x), 0.f);
      float v1 = fmaxf(fmaf(bfhi(r.x), s0.y, h0.y), 0.f);
      float v2 = fmaxf(fmaf(bflo(r.y), s0.z, h0.z), 0.f);
      float v3 = fmaxf(fmaf(bfhi(r.y), s0.w, h0.w), 0.f);
      float v4 = fmaxf(fmaf(bflo(r.z), s1.x, h1.x), 0.f);
      float v5 = fmaxf(fmaf(bfhi(r.z), s1.y, h1.y), 0.f);
      float v6 = fmaxf(fmaf(bflo(r.w), s1.z, h1.z), 0.f);
      float v7 = fmaxf(fmaf(bfhi(r.w), s1.w, h1.w), 0.f);
      union { u32 u[4]; short8 s; } cv;
      cv.u[0] = cvtpk_bf16(v0, v1); cv.u[1] = cvtpk_bf16(v2, v3);
      cv.u[2] = cvtpk_bf16(v4, v5); cv.u[3] = cvtpk_bf16(v6, v7);
      bfr[f] = cv.s;
    }
#pragma unroll
    for (int i = 0; i < 4; ++i)
#pragma unroll
      for (int j = 0; j < 4; ++j)
        acc[i][j] = __builtin_amdgcn_mfma_f32_16x16x32_bf16(af[i], bfr[j], acc[i][j], 0, 0, 0);
    ++cur; if (cur == 3) cur = 0;
  }
#undef STAGE2

  if (tid < 256) { s_sum[tid] = 0.f; s_ssq[tid] = 0.f; }
  __syncthreads();
  u16* tb2 = y2T + ((size_t)b * 64 + (bn0 >> 7)) * 32768;
#pragma unroll
  for (int i = 0; i < 4; ++i) {
    int ob = wm * 64 + i * 16 + fq * 4;
    float4 b4 = *(const float4*)(b2 + ob);
    float sv0 = 0, sv1 = 0, sv2 = 0, sv3 = 0, qv0 = 0, qv1 = 0, qv2 = 0, qv3 = 0;
#pragma unroll
    for (int j = 0; j < 4; ++j) {
      int nl = wn * 64 + j * 16 + fm;
      ushort4 pk;
      pk.x = f2bf(acc[i][j][0] + b4.x);
      pk.y = f2bf(acc[i][j][1] + b4.y);
      pk.z = f2bf(acc[i][j][2] + b4.z);
      pk.w = f2bf(acc[i][j][3] + b4.w);
      *(ushort4*)(tb2 + (size_t)(ob >> 5) * 4096 + nl * 32 + (ob & 31)) = pk;
      float v0 = bflo(pk.x), v1 = bflo(pk.y), v2 = bflo(pk.z), v3 = bflo(pk.w);
      sv0 += v0; sv1 += v1; sv2 += v2; sv3 += v3;
      qv0 = fmaf(v0, v0, qv0); qv1 = fmaf(v1, v1, qv1);
      qv2 = fmaf(v2, v2, qv2); qv3 = fmaf(v3, v3, qv3);
    }
#pragma unroll
    for (int m = 1; m <= 8; m <<= 1) {
      sv0 += __shfl_xor(sv0, m); sv1 += __shfl_xor(sv1, m);
      sv2 += __shfl_xor(sv2, m); sv3 += __shfl_xor(sv3, m);
      qv0 += __shfl_xor(qv0, m); qv1 += __shfl_xor(qv1, m);
      qv2 += __shfl_xor(qv2, m); qv3 += __shfl_xor(qv3, m);
    }
    if (fm == 0) {
      atomicAdd(&s_sum[ob + 0], sv0); atomicAdd(&s_sum[ob + 1], sv1);
      atomicAdd(&s_sum[ob + 2], sv2); atomicAdd(&s_sum[ob + 3], sv3);
      atomicAdd(&s_ssq[ob + 0], qv0); atomicAdd(&s_ssq[ob + 1], qv1);
      atomicAdd(&s_ssq[ob + 2], qv2); atomicAdd(&s_ssq[ob + 3], qv3);
    }
  }
  __syncthreads();
  if (tid < 256) {
    const int blk = blockIdx.x + 64 * blockIdx.z;
    psum[(size_t)blk * 256 + tid] = s_sum[tid];
    pssq[(size_t)blk * 256 + tid] = s_ssq[tid];
  }
}

// ---------------------------------------------------------------------------
// BN2 + ReLU + transpose: y2T (tiled bf16) -> out fp32 [b][o][n]
// ---------------------------------------------------------------------------
__global__ __launch_bounds__(256) void k_bn2t(const u16* __restrict__ y2T,
                                              const float* __restrict__ scale,
                                              const float* __restrict__ shift,
                                              float* __restrict__ out) {
  __shared__ float t[32][33];
  const int b = blockIdx.z, n0 = blockIdx.x * 32, o0 = blockIdx.y * 32;
  const int cc = threadIdx.x & 31, rr = threadIdx.x >> 5;
  const float sc = scale[o0 + cc], sh = shift[o0 + cc];
  const u16* tb = y2T + ((size_t)b * 64 + (n0 >> 7)) * 32768 +
                  (size_t)(o0 >> 5) * 4096 + (size_t)(n0 & 96) * 32;
#pragma unroll
  for (int i = 0; i < 4; ++i) {
    int r = rr + i * 8;
    float v = bflo((u32)tb[r * 32 + cc]);
    t[r][cc] = fmaxf(fmaf(v, sc, sh), 0.f);
  }
  __syncthreads();
#pragma unroll
  for (int i = 0; i < 4; ++i) {
    int r = rr + i * 8;
    out[((size_t)b * COUT_ + o0 + r) * N_ + n0 + cc] = t[cc][r];
  }
}

// ---------------------------------------------------------------------------
extern "C" void kernel_launch(void* const* d_in, const int* in_sizes, int n_in,
                              void* d_out, int out_size, void* d_ws, size_t ws_size,
                              hipStream_t stream) {
  const float* xyz1    = (const float*)d_in[0];
  const float* xyz2    = (const float*)d_in[1];
  const float* points1 = (const float*)d_in[2];
  const float* points2 = (const float*)d_in[3];
  const float* w1      = (const float*)d_in[4];
  const float* b1      = (const float*)d_in[5];
  const float* g1      = (const float*)d_in[6];
  const float* beta1   = (const float*)d_in[7];
  const float* w2      = (const float*)d_in[8];
  const float* b2      = (const float*)d_in[9];
  const float* g2      = (const float*)d_in[10];
  const float* beta2   = (const float*)d_in[11];
  float* out = (float*)d_out;

  char* ws = (char*)d_ws;
  size_t off = 0;
  u16*    xT    = (u16*)(ws + off);    off += (size_t)B_ * N_ * CIN_ * 2;   // 50.3 MB
  u16*    y1T   = (u16*)(ws + off);    off += (size_t)B_ * N_ * CMID_ * 2;  // 33.6 MB (tiled)
  float*  p2T   = (float*)(ws + off);  off += (size_t)B_ * S_ * D2_ * 4;    // 16.8 MB
  float4* pts4  = (float4*)(ws + off); off += (size_t)B_ * S_ * 16;         // 0.26 MB
  int4*   idx4  = (int4*)(ws + off);   off += (size_t)B_ * N_ * 16;         // 1 MB
  float4* w4    = (float4*)(ws + off); off += (size_t)B_ * N_ * 16;         // 1 MB
  u16*    w1b   = (u16*)(ws + off);    off += (size_t)CMID_ * CIN_ * 2;
  u16*    w2b   = (u16*)(ws + off);    off += (size_t)COUT_ * CMID_ * 2;
  float*  stats = (float*)(ws + off);  off += 1024 * sizeof(float);
  float*  psx   = (float*)(ws + off);  off += (size_t)4 * 512 * 256 * 4;    // 2 MB partials
  u16*    y2T   = xT;  // alias: xT dead after k_gemm1
  float* psum1 = psx;                  // [512][256] each
  float* pssq1 = psum1 + 512 * 256;
  float* psum2 = pssq1 + 512 * 256;
  float* pssq2 = psum2 + 512 * 256;
  float* scale1 = stats,        * shift1 = stats + 256;
  float* scale2 = stats + 512,  * shift2 = stats + 768;

  k_pre_all    <<<dim3(12992), 256, 0, stream>>>(xyz2, pts4, w1, w2, w1b, w2b,
                                                 points2, p2T, points1, xT);
  k_nnref      <<<dim3(N_ / 256, B_), 256, 0, stream>>>(xyz1, pts4, idx4, w4);
  k_gather_pack<<<dim3(N_ / 16, B_), 256, 0, stream>>>(p2T, idx4, w4, xT);
  k_gemm1      <<<dim3(N_ / 128, 1, B_), 512, 0, stream>>>(w1b, b1, xT, y1T,
                                                           psum1, pssq1);
  k_bnstat     <<<dim3(CMID_), 64, 0, stream>>>(psum1, pssq1, g1, beta1, scale1, shift1);
  k_gemm2      <<<dim3(N_ / 128, 1, B_), 512, 0, stream>>>(w2b, b2, y1T,
                                                           scale1, shift1,
                                                           y2T, psum2, pssq2);
  k_bnstat     <<<dim3(COUT_), 64, 0, stream>>>(psum2, pssq2, g2, beta2, scale2, shift2);
  k_bn2t       <<<dim3(N_ / 32, COUT_ / 32, B_), 256, 0, stream>>>(y2T, scale2, shift2, out);
}

// Round 9
// 300.911 us; speedup vs baseline: 1.0859x; 1.0859x over previous
//
#include <hip/hip_runtime.h>

#define B_    8
#define N_    8192
#define S_    2048
#define D1_   128
#define D2_   256
#define CIN_  384
#define CMID_ 256
#define COUT_ 256

typedef unsigned int  u32;
typedef unsigned short u16;
typedef __attribute__((ext_vector_type(8))) short short8;
typedef __attribute__((ext_vector_type(4))) float f32x4;

static __device__ __forceinline__ u32 uminu(u32 a, u32 b) { return a < b ? a : b; }
static __device__ __forceinline__ u32 umed3(u32 a, u32 b, u32 c) {
  u32 d;
  asm("v_med3_u32 %0, %1, %2, %3" : "=v"(d) : "v"(a), "v"(b), "v"(c));
  return d;
}
static __device__ __forceinline__ u16 f2bf(float f) {
  union { float f; u32 u; } v; v.f = f;
  u32 r = v.u + 0x7FFFu + ((v.u >> 16) & 1u);  // RNE
  return (u16)(r >> 16);
}
static __device__ __forceinline__ float bflo(u32 u) { return __uint_as_float(u << 16); }
static __device__ __forceinline__ float bfhi(u32 u) { return __uint_as_float(u & 0xFFFF0000u); }
static __device__ __forceinline__ u32 cvtpk_bf16(float lo, float hi) {
  u32 d;
  asm("v_cvt_pk_bf16_f32 %0, %1, %2" : "=v"(d) : "v"(lo), "v"(hi));
  return d;
}

#define GLD16(g, l)                                                             \
  __builtin_amdgcn_global_load_lds((const __attribute__((address_space(1))) void*)(g), \
                                   (__attribute__((address_space(3))) void*)(l), 16, 0, 0)

// Counted-vmcnt pipeline barrier (T3/T4), race-safe order (round-6 proven):
// wait+barrier FIRST, then stage into the freed buffer.
#define WB(N)                                                                   \
  __builtin_amdgcn_sched_barrier(0);                                            \
  asm volatile("s_waitcnt vmcnt(" #N ")" ::: "memory");                         \
  __builtin_amdgcn_s_barrier();                                                 \
  __builtin_amdgcn_sched_barrier(0);

// ---------------------------------------------------------------------------
// Fused preprocessing, one launch, block-range decode:
//   blocks [0, 4096)        : p2t  transpose points2 -> p2T
//   blocks [4096, 12288)    : packp1 points1 -> xT[.., 0..127] bf16
//   blocks [12288, 12992)   : pre  pts4 + w1/w2 bf16 convert
// ---------------------------------------------------------------------------
__global__ __launch_bounds__(256) void k_pre_all(const float* __restrict__ xyz2,
                                                 float4* __restrict__ pts4,
                                                 const float* __restrict__ w1,
                                                 const float* __restrict__ w2,
                                                 u16* __restrict__ w1b,
                                                 u16* __restrict__ w2b,
                                                 const float* __restrict__ p2,
                                                 float* __restrict__ p2T,
                                                 const float* __restrict__ p1,
                                                 u16* __restrict__ xT) {
  __shared__ float t[32][33];
  const int blk = blockIdx.x;
  const int cc = threadIdx.x & 31, rr = threadIdx.x >> 5;
  if (blk < 4096) {
    // p2t: [b][256][2048] -> [b][2048][256]
    const int s0 = (blk & 63) * 32, d0 = ((blk >> 6) & 7) * 32, b = blk >> 9;
#pragma unroll
    for (int i = 0; i < 4; ++i) {
      int r = rr + i * 8;
      t[r][cc] = p2[((size_t)b * D2_ + d0 + r) * S_ + s0 + cc];
    }
    __syncthreads();
#pragma unroll
    for (int i = 0; i < 4; ++i) {
      int r = rr + i * 8;
      p2T[((size_t)b * S_ + s0 + r) * D2_ + d0 + cc] = t[cc][r];
    }
    return;
  }
  if (blk < 12288) {
    // packp1: [b][128][N] -> xT[b][n][0..127] bf16
    const int idx = blk - 4096;
    const int n0 = (idx & 255) * 32, c0 = ((idx >> 8) & 3) * 32, b = idx >> 10;
#pragma unroll
    for (int i = 0; i < 4; ++i) {
      int r = rr + i * 8;
      t[r][cc] = p1[((size_t)b * D1_ + c0 + r) * N_ + n0 + cc];
    }
    __syncthreads();
#pragma unroll
    for (int i = 0; i < 4; ++i) {
      int r = rr + i * 8;
      xT[((size_t)b * N_ + n0 + r) * CIN_ + c0 + cc] = f2bf(t[cc][r]);
    }
    return;
  }
  const int i = (blk - 12288) * 256 + threadIdx.x;
  if (i < B_ * S_) {
    const int b = i >> 11, s = i & (S_ - 1);
    const float* xb = xyz2 + (size_t)b * 3 * S_;
    float x = xb[s], y = xb[S_ + s], z = xb[2 * S_ + s];
    pts4[b * S_ + s] = make_float4(-2.f * x, -2.f * y, -2.f * z, x * x + y * y + z * z);
    return;
  }
  const int j = i - B_ * S_;
  if (j < CMID_ * CIN_) { w1b[j] = f2bf(w1[j]); return; }
  const int h = j - CMID_ * CIN_;
  if (h < COUT_ * CMID_) w2b[h] = f2bf(w2[h]);
}

// ---------------------------------------------------------------------------
// FUSED NN screen + refine, occupancy-correct: block = 256 threads = 4 waves,
// wave c scans chunk c (512 candidates, wave-uniform address -> s_load) for
// the block's 64 points -- per-thread scan work identical to the round-6
// nn_scan. Per-chunk quantized top-3 keys to LDS; one barrier; wave 0 does
// the 12-candidate exact fp64 refine (selection under total order (d,s) is
// insertion-order independent). Grid 1024 blocks = round-6 occupancy.
// ---------------------------------------------------------------------------
__global__ __launch_bounds__(256) void k_nnref(const float* __restrict__ xyz1,
                                               const float4* __restrict__ pts4,
                                               int4* __restrict__ idx4,
                                               float4* __restrict__ w4) {
  __shared__ uint4 sk[4][64];
  const int b = blockIdx.y, t = threadIdx.x;
  const int nl = t & 63, chunk = t >> 6;
  const int n = blockIdx.x * 64 + nl;
  const float* pb = xyz1 + (size_t)b * 3 * N_;
  {
    const float px = pb[n], py = pb[N_ + n], pz = pb[2 * N_ + n];
    const float pn = px * px + py * py + pz * pz;
    const float4* __restrict__ P = pts4 + b * S_ + chunk * 512;
    u32 m0 = ~0u, m1 = ~0u, m2 = ~0u;
#pragma unroll 8
    for (int s = 0; s < 512; ++s) {
      float4 q = P[s];  // wave-uniform address -> s_load_dwordx4
      float d = fmaf(px, q.x, fmaf(py, q.y, fmaf(pz, q.z, pn + q.w)));
      d = fmaxf(d, 0.f);
      u32 k = (__float_as_uint(d) & 0xFFFFFE00u) | (u32)s;
      u32 m2n = umed3(m1, m2, k);     // old m1, m2: new 3rd-smallest
      m1 = umed3(m0, m1, k);          // old m0, m1
      m0 = uminu(m0, k);
      m2 = m2n;
    }
    uint4 v; v.x = m0; v.y = m1; v.z = m2; v.w = m2;
    sk[chunk][nl] = v;
  }
  __syncthreads();
  if (t < 64) {
    const double px = (double)pb[n], py = (double)pb[N_ + n], pz = (double)pb[2 * N_ + n];
    const double pn = px * px + py * py + pz * pz;
    double bd0 = 1e300, bd1 = 1e300, bd2 = 1e300;
    int bi0 = 1 << 30, bi1 = 1 << 30, bi2 = 1 << 30;
#pragma unroll
    for (int c = 0; c < 4; ++c) {
      uint4 kk = sk[c][t];
      u32 arr[3] = {kk.x, kk.y, kk.z};
#pragma unroll
      for (int j = 0; j < 3; ++j) {
        int s = c * 512 + (int)(arr[j] & 511u);
        float4 q = pts4[b * S_ + s];
        double x = (double)(q.x * -0.5f), y = (double)(q.y * -0.5f), z = (double)(q.z * -0.5f);
        double dot = px * x + py * y + pz * z;
        double d = -2.0 * dot + (pn + (x * x + y * y + z * z));
        if (d < bd2 || (d == bd2 && s < bi2)) {
          if (d < bd1 || (d == bd1 && s < bi1)) {
            bd2 = bd1; bi2 = bi1;
            if (d < bd0 || (d == bd0 && s < bi0)) { bd1 = bd0; bi1 = bi0; bd0 = d; bi0 = s; }
            else                                  { bd1 = d;  bi1 = s; }
          } else { bd2 = d; bi2 = s; }
        }
      }
    }
    float f0 = (float)bd0, f1 = (float)bd1, f2 = (float)bd2;
    float r0 = 1.f / (f0 + 1e-8f), r1 = 1.f / (f1 + 1e-8f), r2 = 1.f / (f2 + 1e-8f);
    float rs = r0 + r1 + r2;
    w4[(size_t)b * N_ + n]   = make_float4(r0 / rs, r1 / rs, r2 / rs, 0.f);
    idx4[(size_t)b * N_ + n] = make_int4(bi0, bi1, bi2, 0);
  }
}

// ---------------------------------------------------------------------------
// Gather+interp into xT[b][n][128..383] bf16. One WAVE per point n.
// ---------------------------------------------------------------------------
__global__ __launch_bounds__(256) void k_gather_pack(const float* __restrict__ p2T,
                                                     const int4* __restrict__ idx4,
                                                     const float4* __restrict__ w4,
                                                     u16* __restrict__ xT) {
  const int b = blockIdx.y;
  const int wv = threadIdx.x >> 6, lane = threadIdx.x & 63;
  const int nbase = blockIdx.x * 16 + wv * 4;
  int4   id[4];
  float4 w[4];
#pragma unroll
  for (int i = 0; i < 4; ++i) {
    id[i] = idx4[(size_t)b * N_ + nbase + i];
    w[i]  = w4[(size_t)b * N_ + nbase + i];
  }
#pragma unroll
  for (int i = 0; i < 4; ++i) {
    const int n = nbase + i;
    const float4* r0 = (const float4*)(p2T + ((size_t)b * S_ + id[i].x) * D2_) + lane;
    const float4* r1 = (const float4*)(p2T + ((size_t)b * S_ + id[i].y) * D2_) + lane;
    const float4* r2 = (const float4*)(p2T + ((size_t)b * S_ + id[i].z) * D2_) + lane;
    float4 a = *r0, bb = *r1, cq = *r2;
    ushort4 pk;
    pk.x = f2bf(a.x * w[i].x + bb.x * w[i].y + cq.x * w[i].z);
    pk.y = f2bf(a.y * w[i].x + bb.y * w[i].y + cq.y * w[i].z);
    pk.z = f2bf(a.z * w[i].x + bb.z * w[i].y + cq.z * w[i].z);
    pk.w = f2bf(a.w * w[i].x + bb.w * w[i].y + cq.w * w[i].z);
    *(ushort4*)(xT + ((size_t)b * N_ + n) * CIN_ + D1_ + lane * 4) = pk;
  }
}

// ---------------------------------------------------------------------------
// BN stats reduction + affine: one wave per channel o. partials [512][256].
// ---------------------------------------------------------------------------
__global__ __launch_bounds__(64) void k_bnstat(const float* __restrict__ ps,
                                               const float* __restrict__ pq,
                                               const float* __restrict__ g,
                                               const float* __restrict__ beta,
                                               float* __restrict__ scale,
                                               float* __restrict__ shift) {
  const int o = blockIdx.x, l = threadIdx.x;
  float s = 0.f, q = 0.f;
#pragma unroll
  for (int i = 0; i < 8; ++i) {
    s += ps[(size_t)(i * 64 + l) * 256 + o];
    q += pq[(size_t)(i * 64 + l) * 256 + o];
  }
#pragma unroll
  for (int m = 1; m <= 32; m <<= 1) { s += __shfl_xor(s, m); q += __shfl_xor(q, m); }
  if (l == 0) {
    const float inv = 1.0f / (float)(B_ * N_);
    float mean = s * inv;
    float var = q * inv - mean * mean;
    float sc = g[o] / sqrtf(var + 1e-5f);
    scale[o] = sc;
    shift[o] = beta[o] - mean * sc;
  }
}

// ---------------------------------------------------------------------------
// GEMM1 (bf16 MFMA), FULL-M tile, triple-buffered LDS, counted-vmcnt
// pipeline (round-6 verified form, unchanged).
// ---------------------------------------------------------------------------
__global__ __launch_bounds__(512) void k_gemm1(const u16* __restrict__ Wb,
                                               const float* __restrict__ bias,
                                               const u16* __restrict__ xT,
                                               u16* __restrict__ y1T,
                                               float* __restrict__ psum,
                                               float* __restrict__ pssq) {
  __shared__ u16 As[3][8192];   // 256 rows x 32 k per buffer
  __shared__ u16 Bs[3][4096];   // 128 rows x 32 k per buffer
  __shared__ float s_sum[256], s_ssq[256];
  const int b = blockIdx.z, bn0 = blockIdx.x * 128;
  const int tid = threadIdx.x, w = tid >> 6, l = tid & 63;
  const int wm = w & 3, wn = w >> 2;
  const int lr = l >> 2, lc = l & 3;
  const int fm = l & 15, fq = l >> 4;
  const int clog = (lc ^ ((lr >> 1) & 3)) * 8;   // staging source k-chunk
  const int swz8 = (fq ^ ((fm >> 1) & 3)) * 8;   // fragment phys k-chunk
  f32x4 acc[4][4];
#pragma unroll
  for (int i = 0; i < 4; ++i)
#pragma unroll
    for (int j = 0; j < 4; ++j) acc[i][j] = (f32x4){0.f, 0.f, 0.f, 0.f};

  const int NK = CIN_ / 32;  // 12

#define STAGE1(kk, buf)                                                         \
  {                                                                             \
    const int k0_ = (kk) * 32;                                                  \
    _Pragma("unroll") for (int j_ = 0; j_ < 2; ++j_) {                          \
      int seg_ = w * 2 + j_, row_ = seg_ * 16 + lr;                             \
      GLD16(Wb + (size_t)row_ * CIN_ + k0_ + clog, &As[buf][seg_ * 512]);       \
    }                                                                           \
    int brow_ = w * 16 + lr;                                                    \
    GLD16(xT + ((size_t)b * N_ + bn0 + brow_) * CIN_ + k0_ + clog,              \
          &Bs[buf][w * 512]);                                                   \
  }

  STAGE1(0, 0);
  STAGE1(1, 1);
  int cur = 0;
  for (int kk = 0; kk < NK; ++kk) {
    if (kk + 1 < NK) { WB(3) } else { WB(0) }
    if (kk + 2 < NK) {
      int bt = cur + 2; if (bt >= 3) bt -= 3;
      STAGE1(kk + 2, bt);
    }
    short8 af[4], bfr[4];
#pragma unroll
    for (int f = 0; f < 4; ++f) {
      af[f]  = *(const short8*)&As[cur][(wm * 64 + f * 16 + fm) * 32 + swz8];
      bfr[f] = *(const short8*)&Bs[cur][(wn * 64 + f * 16 + fm) * 32 + swz8];
    }
#pragma unroll
    for (int i = 0; i < 4; ++i)
#pragma unroll
      for (int j = 0; j < 4; ++j)
        acc[i][j] = __builtin_amdgcn_mfma_f32_16x16x32_bf16(af[i], bfr[j], acc[i][j], 0, 0, 0);
    ++cur; if (cur == 3) cur = 0;
  }
#undef STAGE1

  if (tid < 256) { s_sum[tid] = 0.f; s_ssq[tid] = 0.f; }
  __syncthreads();
  u16* tb = y1T + ((size_t)b * 64 + (bn0 >> 7)) * 32768;
#pragma unroll
  for (int i = 0; i < 4; ++i) {
    int ob = wm * 64 + i * 16 + fq * 4;
    float4 b4 = *(const float4*)(bias + ob);
    float sv0 = 0, sv1 = 0, sv2 = 0, sv3 = 0, qv0 = 0, qv1 = 0, qv2 = 0, qv3 = 0;
#pragma unroll
    for (int j = 0; j < 4; ++j) {
      int nl = wn * 64 + j * 16 + fm;
      ushort4 pk;
      pk.x = f2bf(acc[i][j][0] + b4.x);
      pk.y = f2bf(acc[i][j][1] + b4.y);
      pk.z = f2bf(acc[i][j][2] + b4.z);
      pk.w = f2bf(acc[i][j][3] + b4.w);
      *(ushort4*)(tb + (size_t)(ob >> 5) * 4096 + nl * 32 + (ob & 31)) = pk;
      float v0 = bflo(pk.x), v1 = bflo(pk.y), v2 = bflo(pk.z), v3 = bflo(pk.w);
      sv0 += v0; sv1 += v1; sv2 += v2; sv3 += v3;
      qv0 = fmaf(v0, v0, qv0); qv1 = fmaf(v1, v1, qv1);
      qv2 = fmaf(v2, v2, qv2); qv3 = fmaf(v3, v3, qv3);
    }
#pragma unroll
    for (int m = 1; m <= 8; m <<= 1) {
      sv0 += __shfl_xor(sv0, m); sv1 += __shfl_xor(sv1, m);
      sv2 += __shfl_xor(sv2, m); sv3 += __shfl_xor(sv3, m);
      qv0 += __shfl_xor(qv0, m); qv1 += __shfl_xor(qv1, m);
      qv2 += __shfl_xor(qv2, m); qv3 += __shfl_xor(qv3, m);
    }
    if (fm == 0) {
      atomicAdd(&s_sum[ob + 0], sv0); atomicAdd(&s_sum[ob + 1], sv1);
      atomicAdd(&s_sum[ob + 2], sv2); atomicAdd(&s_sum[ob + 3], sv3);
      atomicAdd(&s_ssq[ob + 0], qv0); atomicAdd(&s_ssq[ob + 1], qv1);
      atomicAdd(&s_ssq[ob + 2], qv2); atomicAdd(&s_ssq[ob + 3], qv3);
    }
  }
  __syncthreads();
  if (tid < 256) {
    const int blk = blockIdx.x + 64 * blockIdx.z;   // 0..511
    psum[(size_t)blk * 256 + tid] = s_sum[tid];
    pssq[(size_t)blk * 256 + tid] = s_ssq[tid];
  }
}

// ---------------------------------------------------------------------------
// GEMM2 (bf16 MFMA), FULL-M tile, same pipeline (round-6 form, unchanged).
// ---------------------------------------------------------------------------
__global__ __launch_bounds__(512) void k_gemm2(const u16* __restrict__ Wb2,
                                               const float* __restrict__ b2,
                                               const u16* __restrict__ y1T,
                                               const float* __restrict__ scale,
                                               const float* __restrict__ shift,
                                               u16* __restrict__ y2T,
                                               float* __restrict__ psum,
                                               float* __restrict__ pssq) {
  __shared__ u16 As[3][8192];
  __shared__ u16 Bs[3][4096];
  __shared__ float s_sum[256], s_ssq[256];
  __shared__ float s_sc[CMID_], s_sh[CMID_];
  const int b = blockIdx.z, bn0 = blockIdx.x * 128;
  const int tid = threadIdx.x, w = tid >> 6, l = tid & 63;
  const int wm = w & 3, wn = w >> 2;
  const int lr = l >> 2, lc = l & 3;
  const int fm = l & 15, fq = l >> 4;
  const int clog = (lc ^ ((lr >> 1) & 3)) * 8;
  const int swz8 = (fq ^ ((fm >> 1) & 3)) * 8;
  if (tid < 256) {
    s_sc[tid] = scale[tid];
    s_sh[tid] = shift[tid];
  }
  f32x4 acc[4][4];
#pragma unroll
  for (int i = 0; i < 4; ++i)
#pragma unroll
    for (int j = 0; j < 4; ++j) acc[i][j] = (f32x4){0.f, 0.f, 0.f, 0.f};

  const u16* tb = y1T + ((size_t)b * 64 + (bn0 >> 7)) * 32768;
  const int NK = CMID_ / 32;  // 8

#define STAGE2(kk, buf)                                                         \
  {                                                                             \
    const int k0_ = (kk) * 32;                                                  \
    _Pragma("unroll") for (int j_ = 0; j_ < 2; ++j_) {                          \
      int seg_ = w * 2 + j_, row_ = seg_ * 16 + lr;                             \
      GLD16(Wb2 + (size_t)row_ * CMID_ + k0_ + clog, &As[buf][seg_ * 512]);     \
    }                                                                           \
    int brow_ = w * 16 + lr;                                                    \
    GLD16(tb + (size_t)(kk) * 4096 + brow_ * 32 + clog, &Bs[buf][w * 512]);     \
  }

  STAGE2(0, 0);
  STAGE2(1, 1);
  int cur = 0;
  for (int kk = 0; kk < NK; ++kk) {
    if (kk + 1 < NK) { WB(3) } else { WB(0) }   // also covers s_sc/s_sh init
    if (kk + 2 < NK) {
      int bt = cur + 2; if (bt >= 3) bt -= 3;
      STAGE2(kk + 2, bt);
    }
    const int kb = kk * 32 + fq * 8;
    float4 s0 = *(const float4*)&s_sc[kb], s1 = *(const float4*)&s_sc[kb + 4];
    float4 h0 = *(const float4*)&s_sh[kb], h1 = *(const float4*)&s_sh[kb + 4];
    short8 af[4], bfr[4];
#pragma unroll
    for (int f = 0; f < 4; ++f) {
      af[f] = *(const short8*)&As[cur][(wm * 64 + f * 16 + fm) * 32 + swz8];
      uint4 r = *(const uint4*)&Bs[cur][(wn * 64 + f * 16 + fm) * 32 + swz8];
      float v0 = fmaxf(fmaf(bflo(r.x), s0.x, h0.x), 0.f);
      float v1 = fmaxf(fmaf(bfhi(r.x), s0.y, h0.y), 0.f);
      float v2 = fmaxf(fmaf(bflo(r.y), s0.z, h0.z), 0.f);
      float v3 = fmaxf(fmaf(bfhi(r.y), s0.w, h0.w), 0.f);
      float v4 = fmaxf(fmaf(bflo(r.z), s1.x, h1.x), 0.f);
      float v5 = fmaxf(fmaf(bfhi(r.z), s1.y, h1.y), 0.f);
      float v6 = fmaxf(fmaf(bflo(r.w), s1.z, h1.z), 0.f);
      float v7 = fmaxf(fmaf(bfhi(r.w), s1.w, h1.w), 0.f);
      union { u32 u[4]; short8 s; } cv;
      cv.u[0] = cvtpk_bf16(v0, v1); cv.u[1] = cvtpk_bf16(v2, v3);
      cv.u[2] = cvtpk_bf16(v4, v5); cv.u[3] = cvtpk_bf16(v6, v7);
      bfr[f] = cv.s;
    }
#pragma unroll
    for (int i = 0; i < 4; ++i)
#pragma unroll
      for (int j = 0; j < 4; ++j)
        acc[i][j] = __builtin_amdgcn_mfma_f32_16x16x32_bf16(af[i], bfr[j], acc[i][j], 0, 0, 0);
    ++cur; if (cur == 3) cur = 0;
  }
#undef STAGE2

  if (tid < 256) { s_sum[tid] = 0.f; s_ssq[tid] = 0.f; }
  __syncthreads();
  u16* tb2 = y2T + ((size_t)b * 64 + (bn0 >> 7)) * 32768;
#pragma unroll
  for (int i = 0; i < 4; ++i) {
    int ob = wm * 64 + i * 16 + fq * 4;
    float4 b4 = *(const float4*)(b2 + ob);
    float sv0 = 0, sv1 = 0, sv2 = 0, sv3 = 0, qv0 = 0, qv1 = 0, qv2 = 0, qv3 = 0;
#pragma unroll
    for (int j = 0; j < 4; ++j) {
      int nl = wn * 64 + j * 16 + fm;
      ushort4 pk;
      pk.x = f2bf(acc[i][j][0] + b4.x);
      pk.y = f2bf(acc[i][j][1] + b4.y);
      pk.z = f2bf(acc[i][j][2] + b4.z);
      pk.w = f2bf(acc[i][j][3] + b4.w);
      *(ushort4*)(tb2 + (size_t)(ob >> 5) * 4096 + nl * 32 + (ob & 31)) = pk;
      float v0 = bflo(pk.x), v1 = bflo(pk.y), v2 = bflo(pk.z), v3 = bflo(pk.w);
      sv0 += v0; sv1 += v1; sv2 += v2; sv3 += v3;
      qv0 = fmaf(v0, v0, qv0); qv1 = fmaf(v1, v1, qv1);
      qv2 = fmaf(v2, v2, qv2); qv3 = fmaf(v3, v3, qv3);
    }
#pragma unroll
    for (int m = 1; m <= 8; m <<= 1) {
      sv0 += __shfl_xor(sv0, m); sv1 += __shfl_xor(sv1, m);
      sv2 += __shfl_xor(sv2, m); sv3 += __shfl_xor(sv3, m);
      qv0 += __shfl_xor(qv0, m); qv1 += __shfl_xor(qv1, m);
      qv2 += __shfl_xor(qv2, m); qv3 += __shfl_xor(qv3, m);
    }
    if (fm == 0) {
      atomicAdd(&s_sum[ob + 0], sv0); atomicAdd(&s_sum[ob + 1], sv1);
      atomicAdd(&s_sum[ob + 2], sv2); atomicAdd(&s_sum[ob + 3], sv3);
      atomicAdd(&s_ssq[ob + 0], qv0); atomicAdd(&s_ssq[ob + 1], qv1);
      atomicAdd(&s_ssq[ob + 2], qv2); atomicAdd(&s_ssq[ob + 3], qv3);
    }
  }
  __syncthreads();
  if (tid < 256) {
    const int blk = blockIdx.x + 64 * blockIdx.z;
    psum[(size_t)blk * 256 + tid] = s_sum[tid];
    pssq[(size_t)blk * 256 + tid] = s_ssq[tid];
  }
}

// ---------------------------------------------------------------------------
// BN2 + ReLU + transpose: y2T (tiled bf16) -> out fp32 [b][o][n]
// ---------------------------------------------------------------------------
__global__ __launch_bounds__(256) void k_bn2t(const u16* __restrict__ y2T,
                                              const float* __restrict__ scale,
                                              const float* __restrict__ shift,
                                              float* __restrict__ out) {
  __shared__ float t[32][33];
  const int b = blockIdx.z, n0 = blockIdx.x * 32, o0 = blockIdx.y * 32;
  const int cc = threadIdx.x & 31, rr = threadIdx.x >> 5;
  const float sc = scale[o0 + cc], sh = shift[o0 + cc];
  const u16* tb = y2T + ((size_t)b * 64 + (n0 >> 7)) * 32768 +
                  (size_t)(o0 >> 5) * 4096 + (size_t)(n0 & 96) * 32;
#pragma unroll
  for (int i = 0; i < 4; ++i) {
    int r = rr + i * 8;
    float v = bflo((u32)tb[r * 32 + cc]);
    t[r][cc] = fmaxf(fmaf(v, sc, sh), 0.f);
  }
  __syncthreads();
#pragma unroll
  for (int i = 0; i < 4; ++i) {
    int r = rr + i * 8;
    out[((size_t)b * COUT_ + o0 + r) * N_ + n0 + cc] = t[cc][r];
  }
}

// ---------------------------------------------------------------------------
extern "C" void kernel_launch(void* const* d_in, const int* in_sizes, int n_in,
                              void* d_out, int out_size, void* d_ws, size_t ws_size,
                              hipStream_t stream) {
  const float* xyz1    = (const float*)d_in[0];
  const float* xyz2    = (const float*)d_in[1];
  const float* points1 = (const float*)d_in[2];
  const float* points2 = (const float*)d_in[3];
  const float* w1      = (const float*)d_in[4];
  const float* b1      = (const float*)d_in[5];
  const float* g1      = (const float*)d_in[6];
  const float* beta1   = (const float*)d_in[7];
  const float* w2      = (const float*)d_in[8];
  const float* b2      = (const float*)d_in[9];
  const float* g2      = (const float*)d_in[10];
  const float* beta2   = (const float*)d_in[11];
  float* out = (float*)d_out;

  char* ws = (char*)d_ws;
  size_t off = 0;
  u16*    xT    = (u16*)(ws + off);    off += (size_t)B_ * N_ * CIN_ * 2;   // 50.3 MB
  u16*    y1T   = (u16*)(ws + off);    off += (size_t)B_ * N_ * CMID_ * 2;  // 33.6 MB (tiled)
  float*  p2T   = (float*)(ws + off);  off += (size_t)B_ * S_ * D2_ * 4;    // 16.8 MB
  float4* pts4  = (float4*)(ws + off); off += (size_t)B_ * S_ * 16;         // 0.26 MB
  int4*   idx4  = (int4*)(ws + off);   off += (size_t)B_ * N_ * 16;         // 1 MB
  float4* w4    = (float4*)(ws + off); off += (size_t)B_ * N_ * 16;         // 1 MB
  u16*    w1b   = (u16*)(ws + off);    off += (size_t)CMID_ * CIN_ * 2;
  u16*    w2b   = (u16*)(ws + off);    off += (size_t)COUT_ * CMID_ * 2;
  float*  stats = (float*)(ws + off);  off += 1024 * sizeof(float);
  float*  psx   = (float*)(ws + off);  off += (size_t)4 * 512 * 256 * 4;    // 2 MB partials
  u16*    y2T   = xT;  // alias: xT dead after k_gemm1
  float* psum1 = psx;                  // [512][256] each
  float* pssq1 = psum1 + 512 * 256;
  float* psum2 = pssq1 + 512 * 256;
  float* pssq2 = psum2 + 512 * 256;
  float* scale1 = stats,        * shift1 = stats + 256;
  float* scale2 = stats + 512,  * shift2 = stats + 768;

  k_pre_all    <<<dim3(12992), 256, 0, stream>>>(xyz2, pts4, w1, w2, w1b, w2b,
                                                 points2, p2T, points1, xT);
  k_nnref      <<<dim3(N_ / 64, B_), 256, 0, stream>>>(xyz1, pts4, idx4, w4);
  k_gather_pack<<<dim3(N_ / 16, B_), 256, 0, stream>>>(p2T, idx4, w4, xT);
  k_gemm1      <<<dim3(N_ / 128, 1, B_), 512, 0, stream>>>(w1b, b1, xT, y1T,
                                                           psum1, pssq1);
  k_bnstat     <<<dim3(CMID_), 64, 0, stream>>>(psum1, pssq1, g1, beta1, scale1, shift1);
  k_gemm2      <<<dim3(N_ / 128, 1, B_), 512, 0, stream>>>(w2b, b2, y1T,
                                                           scale1, shift1,
                                                           y2T, psum2, pssq2);
  k_bnstat     <<<dim3(COUT_), 64, 0, stream>>>(psum2, pssq2, g2, beta2, scale2, shift2);
  k_bn2t       <<<dim3(N_ / 32, COUT_ / 32, B_), 256, 0, stream>>>(y2T, scale2, shift2, out);
}

// Round 10
// 249.992 us; speedup vs baseline: 1.3071x; 1.2037x over previous
//
#include <hip/hip_runtime.h>

#define B_    8
#define N_    8192
#define S_    2048
#define D1_   128
#define D2_   256
#define CIN_  384
#define CMID_ 256
#define COUT_ 256

typedef unsigned int  u32;
typedef unsigned short u16;
typedef __attribute__((ext_vector_type(8))) short short8;
typedef __attribute__((ext_vector_type(4))) float f32x4;

static __device__ __forceinline__ u32 uminu(u32 a, u32 b) { return a < b ? a : b; }
static __device__ __forceinline__ u32 umed3(u32 a, u32 b, u32 c) {
  u32 d;
  asm("v_med3_u32 %0, %1, %2, %3" : "=v"(d) : "v"(a), "v"(b), "v"(c));
  return d;
}
static __device__ __forceinline__ u16 f2bf(float f) {
  union { float f; u32 u; } v; v.f = f;
  u32 r = v.u + 0x7FFFu + ((v.u >> 16) & 1u);  // RNE
  return (u16)(r >> 16);
}
static __device__ __forceinline__ float bflo(u32 u) { return __uint_as_float(u << 16); }
static __device__ __forceinline__ float bfhi(u32 u) { return __uint_as_float(u & 0xFFFF0000u); }
static __device__ __forceinline__ u32 cvtpk_bf16(float lo, float hi) {
  u32 d;
  asm("v_cvt_pk_bf16_f32 %0, %1, %2" : "=v"(d) : "v"(lo), "v"(hi));
  return d;
}

#define GLD16(g, l)                                                             \
  __builtin_amdgcn_global_load_lds((const __attribute__((address_space(1))) void*)(g), \
                                   (__attribute__((address_space(3))) void*)(l), 16, 0, 0)

// Counted-vmcnt pipeline barrier (T3/T4), race-safe order (round-6 proven):
// wait+barrier FIRST, then stage into the freed buffer.
#define WB(N)                                                                   \
  __builtin_amdgcn_sched_barrier(0);                                            \
  asm volatile("s_waitcnt vmcnt(" #N ")" ::: "memory");                         \
  __builtin_amdgcn_s_barrier();                                                 \
  __builtin_amdgcn_sched_barrier(0);

// ---------------------------------------------------------------------------
// Small prep: pts4 = (-2x,-2y,-2z,|q|^2); w1/w2 -> bf16. 704 blocks.
// ---------------------------------------------------------------------------
__global__ __launch_bounds__(256) void k_pre0(const float* __restrict__ xyz2,
                                              float4* __restrict__ pts4,
                                              const float* __restrict__ w1,
                                              const float* __restrict__ w2,
                                              u16* __restrict__ w1b,
                                              u16* __restrict__ w2b) {
  const int i = blockIdx.x * 256 + threadIdx.x;
  if (i < B_ * S_) {
    const int b = i >> 11, s = i & (S_ - 1);
    const float* xb = xyz2 + (size_t)b * 3 * S_;
    float x = xb[s], y = xb[S_ + s], z = xb[2 * S_ + s];
    pts4[b * S_ + s] = make_float4(-2.f * x, -2.f * y, -2.f * z, x * x + y * y + z * z);
    return;
  }
  const int j = i - B_ * S_;
  if (j < CMID_ * CIN_) { w1b[j] = f2bf(w1[j]); return; }
  const int h = j - CMID_ * CIN_;
  if (h < COUT_ * CMID_) w2b[h] = f2bf(w2[h]);
}

// ---------------------------------------------------------------------------
// MEGA kernel: three independent ops co-resident in one launch so the
// compute-bound nnref overlaps the memory-bound transposes (same-stream
// kernels would serialize).  Block ranges:
//   [0, 1024)      nnref: 4 waves, wave c scans chunk c (s_load via
//                  readfirstlane-uniform chunk) for 64 points; LDS keys;
//                  wave 0 does the 12-candidate exact fp64 refine.
//   [1024, 5120)   p2t  : points2 [b][256][2048] -> p2T [b][2048][256]
//   [5120, 13312)  packp1: points1 -> xT[b][n][0..127] bf16
// ---------------------------------------------------------------------------
__global__ __launch_bounds__(256) void k_mega(const float* __restrict__ xyz1,
                                              const float4* __restrict__ pts4,
                                              int4* __restrict__ idx4,
                                              float4* __restrict__ w4,
                                              const float* __restrict__ p2,
                                              float* __restrict__ p2T,
                                              const float* __restrict__ p1,
                                              u16* __restrict__ xT) {
  __shared__ __align__(16) char smem[4352];
  const int blk = blockIdx.x;
  if (blk < 1024) {
    uint4 (*sk)[64] = (uint4(*)[64])smem;
    const int b = blk >> 7, t = threadIdx.x;
    const int nl = t & 63;
    // readfirstlane forces the chunk into an SGPR -> compiler proves the
    // candidate pointer wave-uniform -> s_load path (the round-9 regression
    // was losing this).
    const int chunk = __builtin_amdgcn_readfirstlane(t >> 6);
    const int n = (blk & 127) * 64 + nl;
    const float* pb = xyz1 + (size_t)b * 3 * N_;
    {
      const float px = pb[n], py = pb[N_ + n], pz = pb[2 * N_ + n];
      const float pn = px * px + py * py + pz * pz;
      const float4* __restrict__ P = pts4 + b * S_ + chunk * 512;
      u32 m0 = ~0u, m1 = ~0u, m2 = ~0u;
#pragma unroll 8
      for (int s = 0; s < 512; ++s) {
        float4 q = P[s];  // wave-uniform -> s_load_dwordx4
        float d = fmaf(px, q.x, fmaf(py, q.y, fmaf(pz, q.z, pn + q.w)));
        d = fmaxf(d, 0.f);
        u32 k = (__float_as_uint(d) & 0xFFFFFE00u) | (u32)s;
        u32 m2n = umed3(m1, m2, k);     // old m1, m2: new 3rd-smallest
        m1 = umed3(m0, m1, k);          // old m0, m1
        m0 = uminu(m0, k);
        m2 = m2n;
      }
      uint4 v; v.x = m0; v.y = m1; v.z = m2; v.w = m2;
      sk[chunk][nl] = v;
    }
    __syncthreads();
    if (t < 64) {
      const double px = (double)pb[n], py = (double)pb[N_ + n], pz = (double)pb[2 * N_ + n];
      const double pn = px * px + py * py + pz * pz;
      double bd0 = 1e300, bd1 = 1e300, bd2 = 1e300;
      int bi0 = 1 << 30, bi1 = 1 << 30, bi2 = 1 << 30;
#pragma unroll
      for (int c = 0; c < 4; ++c) {
        uint4 kk = sk[c][t];
        u32 arr[3] = {kk.x, kk.y, kk.z};
#pragma unroll
        for (int j = 0; j < 3; ++j) {
          int s = c * 512 + (int)(arr[j] & 511u);
          float4 q = pts4[b * S_ + s];
          double x = (double)(q.x * -0.5f), y = (double)(q.y * -0.5f), z = (double)(q.z * -0.5f);
          double dot = px * x + py * y + pz * z;
          double d = -2.0 * dot + (pn + (x * x + y * y + z * z));
          if (d < bd2 || (d == bd2 && s < bi2)) {
            if (d < bd1 || (d == bd1 && s < bi1)) {
              bd2 = bd1; bi2 = bi1;
              if (d < bd0 || (d == bd0 && s < bi0)) { bd1 = bd0; bi1 = bi0; bd0 = d; bi0 = s; }
              else                                  { bd1 = d;  bi1 = s; }
            } else { bd2 = d; bi2 = s; }
          }
        }
      }
      float f0 = (float)bd0, f1 = (float)bd1, f2 = (float)bd2;
      float r0 = 1.f / (f0 + 1e-8f), r1 = 1.f / (f1 + 1e-8f), r2 = 1.f / (f2 + 1e-8f);
      float rs = r0 + r1 + r2;
      w4[(size_t)b * N_ + n]   = make_float4(r0 / rs, r1 / rs, r2 / rs, 0.f);
      idx4[(size_t)b * N_ + n] = make_int4(bi0, bi1, bi2, 0);
    }
    return;
  }
  float (*t2)[33] = (float(*)[33])smem;
  const int cc = threadIdx.x & 31, rr = threadIdx.x >> 5;
  if (blk < 5120) {
    const int idx = blk - 1024;
    const int s0 = (idx & 63) * 32, d0 = ((idx >> 6) & 7) * 32, b = idx >> 9;
#pragma unroll
    for (int i = 0; i < 4; ++i) {
      int r = rr + i * 8;
      t2[r][cc] = p2[((size_t)b * D2_ + d0 + r) * S_ + s0 + cc];
    }
    __syncthreads();
#pragma unroll
    for (int i = 0; i < 4; ++i) {
      int r = rr + i * 8;
      p2T[((size_t)b * S_ + s0 + r) * D2_ + d0 + cc] = t2[cc][r];
    }
    return;
  }
  {
    const int idx = blk - 5120;
    const int n0 = (idx & 255) * 32, c0 = ((idx >> 8) & 3) * 32, b = idx >> 10;
#pragma unroll
    for (int i = 0; i < 4; ++i) {
      int r = rr + i * 8;
      t2[r][cc] = p1[((size_t)b * D1_ + c0 + r) * N_ + n0 + cc];
    }
    __syncthreads();
#pragma unroll
    for (int i = 0; i < 4; ++i) {
      int r = rr + i * 8;
      xT[((size_t)b * N_ + n0 + r) * CIN_ + c0 + cc] = f2bf(t2[cc][r]);
    }
  }
}

// ---------------------------------------------------------------------------
// Gather+interp into xT[b][n][128..383] bf16. One WAVE per point n.
// ---------------------------------------------------------------------------
__global__ __launch_bounds__(256) void k_gather_pack(const float* __restrict__ p2T,
                                                     const int4* __restrict__ idx4,
                                                     const float4* __restrict__ w4,
                                                     u16* __restrict__ xT) {
  const int b = blockIdx.y;
  const int wv = threadIdx.x >> 6, lane = threadIdx.x & 63;
  const int nbase = blockIdx.x * 16 + wv * 4;
  int4   id[4];
  float4 w[4];
#pragma unroll
  for (int i = 0; i < 4; ++i) {
    id[i] = idx4[(size_t)b * N_ + nbase + i];
    w[i]  = w4[(size_t)b * N_ + nbase + i];
  }
#pragma unroll
  for (int i = 0; i < 4; ++i) {
    const int n = nbase + i;
    const float4* r0 = (const float4*)(p2T + ((size_t)b * S_ + id[i].x) * D2_) + lane;
    const float4* r1 = (const float4*)(p2T + ((size_t)b * S_ + id[i].y) * D2_) + lane;
    const float4* r2 = (const float4*)(p2T + ((size_t)b * S_ + id[i].z) * D2_) + lane;
    float4 a = *r0, bb = *r1, cq = *r2;
    ushort4 pk;
    pk.x = f2bf(a.x * w[i].x + bb.x * w[i].y + cq.x * w[i].z);
    pk.y = f2bf(a.y * w[i].x + bb.y * w[i].y + cq.y * w[i].z);
    pk.z = f2bf(a.z * w[i].x + bb.z * w[i].y + cq.z * w[i].z);
    pk.w = f2bf(a.w * w[i].x + bb.w * w[i].y + cq.w * w[i].z);
    *(ushort4*)(xT + ((size_t)b * N_ + n) * CIN_ + D1_ + lane * 4) = pk;
  }
}

// ---------------------------------------------------------------------------
// BN stats reduction + affine: one wave per channel o. partials [512][256].
// ---------------------------------------------------------------------------
__global__ __launch_bounds__(64) void k_bnstat(const float* __restrict__ ps,
                                               const float* __restrict__ pq,
                                               const float* __restrict__ g,
                                               const float* __restrict__ beta,
                                               float* __restrict__ scale,
                                               float* __restrict__ shift) {
  const int o = blockIdx.x, l = threadIdx.x;
  float s = 0.f, q = 0.f;
#pragma unroll
  for (int i = 0; i < 8; ++i) {
    s += ps[(size_t)(i * 64 + l) * 256 + o];
    q += pq[(size_t)(i * 64 + l) * 256 + o];
  }
#pragma unroll
  for (int m = 1; m <= 32; m <<= 1) { s += __shfl_xor(s, m); q += __shfl_xor(q, m); }
  if (l == 0) {
    const float inv = 1.0f / (float)(B_ * N_);
    float mean = s * inv;
    float var = q * inv - mean * mean;
    float sc = g[o] / sqrtf(var + 1e-5f);
    scale[o] = sc;
    shift[o] = beta[o] - mean * sc;
  }
}

// ---------------------------------------------------------------------------
// GEMM1 (bf16 MFMA), FULL-M tile, triple-buffered LDS, counted-vmcnt
// pipeline (round-6 verified form, unchanged).
// ---------------------------------------------------------------------------
__global__ __launch_bounds__(512) void k_gemm1(const u16* __restrict__ Wb,
                                               const float* __restrict__ bias,
                                               const u16* __restrict__ xT,
                                               u16* __restrict__ y1T,
                                               float* __restrict__ psum,
                                               float* __restrict__ pssq) {
  __shared__ u16 As[3][8192];   // 256 rows x 32 k per buffer
  __shared__ u16 Bs[3][4096];   // 128 rows x 32 k per buffer
  __shared__ float s_sum[256], s_ssq[256];
  const int b = blockIdx.z, bn0 = blockIdx.x * 128;
  const int tid = threadIdx.x, w = tid >> 6, l = tid & 63;
  const int wm = w & 3, wn = w >> 2;
  const int lr = l >> 2, lc = l & 3;
  const int fm = l & 15, fq = l >> 4;
  const int clog = (lc ^ ((lr >> 1) & 3)) * 8;   // staging source k-chunk
  const int swz8 = (fq ^ ((fm >> 1) & 3)) * 8;   // fragment phys k-chunk
  f32x4 acc[4][4];
#pragma unroll
  for (int i = 0; i < 4; ++i)
#pragma unroll
    for (int j = 0; j < 4; ++j) acc[i][j] = (f32x4){0.f, 0.f, 0.f, 0.f};

  const int NK = CIN_ / 32;  // 12

#define STAGE1(kk, buf)                                                         \
  {                                                                             \
    const int k0_ = (kk) * 32;                                                  \
    _Pragma("unroll") for (int j_ = 0; j_ < 2; ++j_) {                          \
      int seg_ = w * 2 + j_, row_ = seg_ * 16 + lr;                             \
      GLD16(Wb + (size_t)row_ * CIN_ + k0_ + clog, &As[buf][seg_ * 512]);       \
    }                                                                           \
    int brow_ = w * 16 + lr;                                                    \
    GLD16(xT + ((size_t)b * N_ + bn0 + brow_) * CIN_ + k0_ + clog,              \
          &Bs[buf][w * 512]);                                                   \
  }

  STAGE1(0, 0);
  STAGE1(1, 1);
  int cur = 0;
  for (int kk = 0; kk < NK; ++kk) {
    if (kk + 1 < NK) { WB(3) } else { WB(0) }
    if (kk + 2 < NK) {
      int bt = cur + 2; if (bt >= 3) bt -= 3;
      STAGE1(kk + 2, bt);
    }
    short8 af[4], bfr[4];
#pragma unroll
    for (int f = 0; f < 4; ++f) {
      af[f]  = *(const short8*)&As[cur][(wm * 64 + f * 16 + fm) * 32 + swz8];
      bfr[f] = *(const short8*)&Bs[cur][(wn * 64 + f * 16 + fm) * 32 + swz8];
    }
#pragma unroll
    for (int i = 0; i < 4; ++i)
#pragma unroll
      for (int j = 0; j < 4; ++j)
        acc[i][j] = __builtin_amdgcn_mfma_f32_16x16x32_bf16(af[i], bfr[j], acc[i][j], 0, 0, 0);
    ++cur; if (cur == 3) cur = 0;
  }
#undef STAGE1

  if (tid < 256) { s_sum[tid] = 0.f; s_ssq[tid] = 0.f; }
  __syncthreads();
  u16* tb = y1T + ((size_t)b * 64 + (bn0 >> 7)) * 32768;
#pragma unroll
  for (int i = 0; i < 4; ++i) {
    int ob = wm * 64 + i * 16 + fq * 4;
    float4 b4 = *(const float4*)(bias + ob);
    float sv0 = 0, sv1 = 0, sv2 = 0, sv3 = 0, qv0 = 0, qv1 = 0, qv2 = 0, qv3 = 0;
#pragma unroll
    for (int j = 0; j < 4; ++j) {
      int nl = wn * 64 + j * 16 + fm;
      ushort4 pk;
      pk.x = f2bf(acc[i][j][0] + b4.x);
      pk.y = f2bf(acc[i][j][1] + b4.y);
      pk.z = f2bf(acc[i][j][2] + b4.z);
      pk.w = f2bf(acc[i][j][3] + b4.w);
      *(ushort4*)(tb + (size_t)(ob >> 5) * 4096 + nl * 32 + (ob & 31)) = pk;
      float v0 = bflo(pk.x), v1 = bflo(pk.y), v2 = bflo(pk.z), v3 = bflo(pk.w);
      sv0 += v0; sv1 += v1; sv2 += v2; sv3 += v3;
      qv0 = fmaf(v0, v0, qv0); qv1 = fmaf(v1, v1, qv1);
      qv2 = fmaf(v2, v2, qv2); qv3 = fmaf(v3, v3, qv3);
    }
#pragma unroll
    for (int m = 1; m <= 8; m <<= 1) {
      sv0 += __shfl_xor(sv0, m); sv1 += __shfl_xor(sv1, m);
      sv2 += __shfl_xor(sv2, m); sv3 += __shfl_xor(sv3, m);
      qv0 += __shfl_xor(qv0, m); qv1 += __shfl_xor(qv1, m);
      qv2 += __shfl_xor(qv2, m); qv3 += __shfl_xor(qv3, m);
    }
    if (fm == 0) {
      atomicAdd(&s_sum[ob + 0], sv0); atomicAdd(&s_sum[ob + 1], sv1);
      atomicAdd(&s_sum[ob + 2], sv2); atomicAdd(&s_sum[ob + 3], sv3);
      atomicAdd(&s_ssq[ob + 0], qv0); atomicAdd(&s_ssq[ob + 1], qv1);
      atomicAdd(&s_ssq[ob + 2], qv2); atomicAdd(&s_ssq[ob + 3], qv3);
    }
  }
  __syncthreads();
  if (tid < 256) {
    const int blk = blockIdx.x + 64 * blockIdx.z;   // 0..511
    psum[(size_t)blk * 256 + tid] = s_sum[tid];
    pssq[(size_t)blk * 256 + tid] = s_ssq[tid];
  }
}

// ---------------------------------------------------------------------------
// GEMM2 (bf16 MFMA), FULL-M tile, same pipeline (round-6 form, unchanged).
// ---------------------------------------------------------------------------
__global__ __launch_bounds__(512) void k_gemm2(const u16* __restrict__ Wb2,
                                               const float* __restrict__ b2,
                                               const u16* __restrict__ y1T,
                                               const float* __restrict__ scale,
                                               const float* __restrict__ shift,
                                               u16* __restrict__ y2T,
                                               float* __restrict__ psum,
                                               float* __restrict__ pssq) {
  __shared__ u16 As[3][8192];
  __shared__ u16 Bs[3][4096];
  __shared__ float s_sum[256], s_ssq[256];
  __shared__ float s_sc[CMID_], s_sh[CMID_];
  const int b = blockIdx.z, bn0 = blockIdx.x * 128;
  const int tid = threadIdx.x, w = tid >> 6, l = tid & 63;
  const int wm = w & 3, wn = w >> 2;
  const int lr = l >> 2, lc = l & 3;
  const int fm = l & 15, fq = l >> 4;
  const int clog = (lc ^ ((lr >> 1) & 3)) * 8;
  const int swz8 = (fq ^ ((fm >> 1) & 3)) * 8;
  if (tid < 256) {
    s_sc[tid] = scale[tid];
    s_sh[tid] = shift[tid];
  }
  f32x4 acc[4][4];
#pragma unroll
  for (int i = 0; i < 4; ++i)
#pragma unroll
    for (int j = 0; j < 4; ++j) acc[i][j] = (f32x4){0.f, 0.f, 0.f, 0.f};

  const u16* tb = y1T + ((size_t)b * 64 + (bn0 >> 7)) * 32768;
  const int NK = CMID_ / 32;  // 8

#define STAGE2(kk, buf)                                                         \
  {                                                                             \
    const int k0_ = (kk) * 32;                                                  \
    _Pragma("unroll") for (int j_ = 0; j_ < 2; ++j_) {                          \
      int seg_ = w * 2 + j_, row_ = seg_ * 16 + lr;                             \
      GLD16(Wb2 + (size_t)row_ * CMID_ + k0_ + clog, &As[buf][seg_ * 512]);     \
    }                                                                           \
    int brow_ = w * 16 + lr;                                                    \
    GLD16(tb + (size_t)(kk) * 4096 + brow_ * 32 + clog, &Bs[buf][w * 512]);     \
  }

  STAGE2(0, 0);
  STAGE2(1, 1);
  int cur = 0;
  for (int kk = 0; kk < NK; ++kk) {
    if (kk + 1 < NK) { WB(3) } else { WB(0) }   // also covers s_sc/s_sh init
    if (kk + 2 < NK) {
      int bt = cur + 2; if (bt >= 3) bt -= 3;
      STAGE2(kk + 2, bt);
    }
    const int kb = kk * 32 + fq * 8;
    float4 s0 = *(const float4*)&s_sc[kb], s1 = *(const float4*)&s_sc[kb + 4];
    float4 h0 = *(const float4*)&s_sh[kb], h1 = *(const float4*)&s_sh[kb + 4];
    short8 af[4], bfr[4];
#pragma unroll
    for (int f = 0; f < 4; ++f) {
      af[f] = *(const short8*)&As[cur][(wm * 64 + f * 16 + fm) * 32 + swz8];
      uint4 r = *(const uint4*)&Bs[cur][(wn * 64 + f * 16 + fm) * 32 + swz8];
      float v0 = fmaxf(fmaf(bflo(r.x), s0.x, h0.x), 0.f);
      float v1 = fmaxf(fmaf(bfhi(r.x), s0.y, h0.y), 0.f);
      float v2 = fmaxf(fmaf(bflo(r.y), s0.z, h0.z), 0.f);
      float v3 = fmaxf(fmaf(bfhi(r.y), s0.w, h0.w), 0.f);
      float v4 = fmaxf(fmaf(bflo(r.z), s1.x, h1.x), 0.f);
      float v5 = fmaxf(fmaf(bfhi(r.z), s1.y, h1.y), 0.f);
      float v6 = fmaxf(fmaf(bflo(r.w), s1.z, h1.z), 0.f);
      float v7 = fmaxf(fmaf(bfhi(r.w), s1.w, h1.w), 0.f);
      union { u32 u[4]; short8 s; } cv;
      cv.u[0] = cvtpk_bf16(v0, v1); cv.u[1] = cvtpk_bf16(v2, v3);
      cv.u[2] = cvtpk_bf16(v4, v5); cv.u[3] = cvtpk_bf16(v6, v7);
      bfr[f] = cv.s;
    }
#pragma unroll
    for (int i = 0; i < 4; ++i)
#pragma unroll
      for (int j = 0; j < 4; ++j)
        acc[i][j] = __builtin_amdgcn_mfma_f32_16x16x32_bf16(af[i], bfr[j], acc[i][j], 0, 0, 0);
    ++cur; if (cur == 3) cur = 0;
  }
#undef STAGE2

  if (tid < 256) { s_sum[tid] = 0.f; s_ssq[tid] = 0.f; }
  __syncthreads();
  u16* tb2 = y2T + ((size_t)b * 64 + (bn0 >> 7)) * 32768;
#pragma unroll
  for (int i = 0; i < 4; ++i) {
    int ob = wm * 64 + i * 16 + fq * 4;
    float4 b4 = *(const float4*)(b2 + ob);
    float sv0 = 0, sv1 = 0, sv2 = 0, sv3 = 0, qv0 = 0, qv1 = 0, qv2 = 0, qv3 = 0;
#pragma unroll
    for (int j = 0; j < 4; ++j) {
      int nl = wn * 64 + j * 16 + fm;
      ushort4 pk;
      pk.x = f2bf(acc[i][j][0] + b4.x);
      pk.y = f2bf(acc[i][j][1] + b4.y);
      pk.z = f2bf(acc[i][j][2] + b4.z);
      pk.w = f2bf(acc[i][j][3] + b4.w);
      *(ushort4*)(tb2 + (size_t)(ob >> 5) * 4096 + nl * 32 + (ob & 31)) = pk;
      float v0 = bflo(pk.x), v1 = bflo(pk.y), v2 = bflo(pk.z), v3 = bflo(pk.w);
      sv0 += v0; sv1 += v1; sv2 += v2; sv3 += v3;
      qv0 = fmaf(v0, v0, qv0); qv1 = fmaf(v1, v1, qv1);
      qv2 = fmaf(v2, v2, qv2); qv3 = fmaf(v3, v3, qv3);
    }
#pragma unroll
    for (int m = 1; m <= 8; m <<= 1) {
      sv0 += __shfl_xor(sv0, m); sv1 += __shfl_xor(sv1, m);
      sv2 += __shfl_xor(sv2, m); sv3 += __shfl_xor(sv3, m);
      qv0 += __shfl_xor(qv0, m); qv1 += __shfl_xor(qv1, m);
      qv2 += __shfl_xor(qv2, m); qv3 += __shfl_xor(qv3, m);
    }
    if (fm == 0) {
      atomicAdd(&s_sum[ob + 0], sv0); atomicAdd(&s_sum[ob + 1], sv1);
      atomicAdd(&s_sum[ob + 2], sv2); atomicAdd(&s_sum[ob + 3], sv3);
      atomicAdd(&s_ssq[ob + 0], qv0); atomicAdd(&s_ssq[ob + 1], qv1);
      atomicAdd(&s_ssq[ob + 2], qv2); atomicAdd(&s_ssq[ob + 3], qv3);
    }
  }
  __syncthreads();
  if (tid < 256) {
    const int blk = blockIdx.x + 64 * blockIdx.z;
    psum[(size_t)blk * 256 + tid] = s_sum[tid];
    pssq[(size_t)blk * 256 + tid] = s_ssq[tid];
  }
}

// ---------------------------------------------------------------------------
// BN2 + ReLU + transpose: y2T (tiled bf16) -> out fp32 [b][o][n]
// ---------------------------------------------------------------------------
__global__ __launch_bounds__(256) void k_bn2t(const u16* __restrict__ y2T,
                                              const float* __restrict__ scale,
                                              const float* __restrict__ shift,
                                              float* __restrict__ out) {
  __shared__ float t[32][33];
  const int b = blockIdx.z, n0 = blockIdx.x * 32, o0 = blockIdx.y * 32;
  const int cc = threadIdx.x & 31, rr = threadIdx.x >> 5;
  const float sc = scale[o0 + cc], sh = shift[o0 + cc];
  const u16* tb = y2T + ((size_t)b * 64 + (n0 >> 7)) * 32768 +
                  (size_t)(o0 >> 5) * 4096 + (size_t)(n0 & 96) * 32;
#pragma unroll
  for (int i = 0; i < 4; ++i) {
    int r = rr + i * 8;
    float v = bflo((u32)tb[r * 32 + cc]);
    t[r][cc] = fmaxf(fmaf(v, sc, sh), 0.f);
  }
  __syncthreads();
#pragma unroll
  for (int i = 0; i < 4; ++i) {
    int r = rr + i * 8;
    out[((size_t)b * COUT_ + o0 + r) * N_ + n0 + cc] = t[cc][r];
  }
}

// ---------------------------------------------------------------------------
extern "C" void kernel_launch(void* const* d_in, const int* in_sizes, int n_in,
                              void* d_out, int out_size, void* d_ws, size_t ws_size,
                              hipStream_t stream) {
  const float* xyz1    = (const float*)d_in[0];
  const float* xyz2    = (const float*)d_in[1];
  const float* points1 = (const float*)d_in[2];
  const float* points2 = (const float*)d_in[3];
  const float* w1      = (const float*)d_in[4];
  const float* b1      = (const float*)d_in[5];
  const float* g1      = (const float*)d_in[6];
  const float* beta1   = (const float*)d_in[7];
  const float* w2      = (const float*)d_in[8];
  const float* b2      = (const float*)d_in[9];
  const float* g2      = (const float*)d_in[10];
  const float* beta2   = (const float*)d_in[11];
  float* out = (float*)d_out;

  char* ws = (char*)d_ws;
  size_t off = 0;
  u16*    xT    = (u16*)(ws + off);    off += (size_t)B_ * N_ * CIN_ * 2;   // 50.3 MB
  u16*    y1T   = (u16*)(ws + off);    off += (size_t)B_ * N_ * CMID_ * 2;  // 33.6 MB (tiled)
  float*  p2T   = (float*)(ws + off);  off += (size_t)B_ * S_ * D2_ * 4;    // 16.8 MB
  float4* pts4  = (float4*)(ws + off); off += (size_t)B_ * S_ * 16;         // 0.26 MB
  int4*   idx4  = (int4*)(ws + off);   off += (size_t)B_ * N_ * 16;         // 1 MB
  float4* w4    = (float4*)(ws + off); off += (size_t)B_ * N_ * 16;         // 1 MB
  u16*    w1b   = (u16*)(ws + off);    off += (size_t)CMID_ * CIN_ * 2;
  u16*    w2b   = (u16*)(ws + off);    off += (size_t)COUT_ * CMID_ * 2;
  float*  stats = (float*)(ws + off);  off += 1024 * sizeof(float);
  float*  psx   = (float*)(ws + off);  off += (size_t)4 * 512 * 256 * 4;    // 2 MB partials
  u16*    y2T   = xT;  // alias: xT dead after k_gemm1
  float* psum1 = psx;                  // [512][256] each
  float* pssq1 = psum1 + 512 * 256;
  float* psum2 = pssq1 + 512 * 256;
  float* pssq2 = psum2 + 512 * 256;
  float* scale1 = stats,        * shift1 = stats + 256;
  float* scale2 = stats + 512,  * shift2 = stats + 768;

  k_pre0       <<<dim3(704), 256, 0, stream>>>(xyz2, pts4, w1, w2, w1b, w2b);
  k_mega       <<<dim3(13312), 256, 0, stream>>>(xyz1, pts4, idx4, w4,
                                                 points2, p2T, points1, xT);
  k_gather_pack<<<dim3(N_ / 16, B_), 256, 0, stream>>>(p2T, idx4, w4, xT);
  k_gemm1      <<<dim3(N_ / 128, 1, B_), 512, 0, stream>>>(w1b, b1, xT, y1T,
                                                           psum1, pssq1);
  k_bnstat     <<<dim3(CMID_), 64, 0, stream>>>(psum1, pssq1, g1, beta1, scale1, shift1);
  k_gemm2      <<<dim3(N_ / 128, 1, B_), 512, 0, stream>>>(w2b, b2, y1T,
                                                           scale1, shift1,
                                                           y2T, psum2, pssq2);
  k_bnstat     <<<dim3(COUT_), 64, 0, stream>>>(psum2, pssq2, g2, beta2, scale2, shift2);
  k_bn2t       <<<dim3(N_ / 32, COUT_ / 32, B_), 256, 0, stream>>>(y2T, scale2, shift2, out);
}